// Round 8
// baseline (223.665 us; speedup 1.0000x reference)
//
#include <hip/hip_runtime.h>
#include <math.h>

// Problem constants (from reference setup_inputs)
constexpr int B_  = 2;
constexpr int NS_ = 2048;
constexpr int NT_ = 32768;
constexpr int K_  = 32;
#define RADIUS_F 0.08f

constexpr int TPB = 512;                                 // 8 waves
constexpr int TGT_PER_WAVE = 8;
constexpr int TGT_PER_BLOCK = 8 * TGT_PER_WAVE;          // 64
constexpr int BLOCKS_PER_BATCH = NT_ / TGT_PER_BLOCK;    // 512
constexpr int NCHUNK = NS_ / 64;                         // 32

// Output layout: tuple concatenated flat, in return order (all float).
// Total elements ~12.7M -> all offsets fit int (saves 64-bit addr chains).
constexpr int SZ_PATCH = B_ * NT_ * K_ * 3;
constexpr int SZ_IDX   = B_ * NT_ * K_ * 2;
constexpr int SZ_SIZE  = B_ * NT_;
constexpr int SZ_RAD   = B_;
constexpr int SZ_DIST  = B_ * NT_ * K_;
constexpr int O_PATCH = 0;
constexpr int O_IDX   = O_PATCH + SZ_PATCH;
constexpr int O_SIZE  = O_IDX + SZ_IDX;
constexpr int O_RAD   = O_SIZE + SZ_SIZE;
constexpr int O_DIST  = O_RAD + SZ_RAD;
constexpr int O_WD    = O_DIST + SZ_DIST;

// Compile-time bitonic take-min direction mask for stage (k,j)
constexpr unsigned long long tm_mask(int k, int j) {
    unsigned long long m = 0;
    for (int l = 0; l < 64; ++l)
        if (((l & k) == 0) == ((l & j) == 0)) m |= 1ull << l;
    return m;
}

__device__ __forceinline__ float readlane_f(float v, int l) {
    return __int_as_float(__builtin_amdgcn_readlane(__float_as_int(v), l));
}
__device__ __forceinline__ float bperm_f(int addr, float v) {
    return __int_as_float(__builtin_amdgcn_ds_bpermute(addr, __float_as_int(v)));
}
// lane i <- lane i-1 across the whole wave; lane 0 <- 0 (wave_shr:1, bound_ctrl)
__device__ __forceinline__ float shr1_f(float v) {
    return __int_as_float(__builtin_amdgcn_update_dpp(0, __float_as_int(v),
                                                      0x138, 0xF, 0xF, true));
}
// sorted single insert: lv' = med3(lv[lane-1], v, lv); v broadcast bits in SGPR
__device__ __forceinline__ float med3_vsv(float pv, int vbits, float lv) {
    float r;
    asm("v_med3_f32 %0, %1, %2, %3" : "=v"(r) : "v"(pv), "s"(vbits), "v"(lv));
    return r;
}
// max(p, sgpr-broadcast w)
__device__ __forceinline__ float maxs_f(float p, int wbits) {
    float r;
    asm("v_max_f32 %0, %1, %2" : "=v"(r) : "s"(wbits), "v"(p));
    return r;
}
__device__ __forceinline__ float min3_f(float a, float b, float c) {
    float r;
    asm("v_min3_f32 %0, %1, %2, %3" : "=v"(r) : "v"(a), "v"(b), "v"(c));
    return r;
}
// lv = keep-bit ? lv : pv  (cndmask with SGPR-pair mask)
__device__ __forceinline__ void cnds(float& lv, float pv, unsigned long long keep) {
    float r;
    asm("v_cndmask_b32 %0, %2, %1, %3" : "=v"(r) : "v"(lv), "v"(pv), "s"(keep));
    lv = r;
}
// sp = (-2x, -2y, -2z, r1): d = (r0 + dot') + r1, bitwise == XLA's (r0-2*dot)+r1
// (pre-scale by -2 is exact; x2 scaling commutes with fp rounding)
__device__ __forceinline__ float dist_f(float tx, float ty, float tz, float r0, float4 sp) {
    float dot2 = __fadd_rn(__fadd_rn(__fmul_rn(tx, sp.x), __fmul_rn(ty, sp.y)), __fmul_rn(tz, sp.z));
    return __fadd_rn(__fadd_rn(r0, dot2), sp.w);
}

// one bitonic stage on LV with xor-partner address AJ, direction mask tm_mask(K,J)
#define BSTG(LV, AJ, K, J) { \
    constexpr unsigned long long tm_ = tm_mask(K, J); \
    float pv_ = bperm_f(AJ, LV); \
    unsigned long long sm_ = __ballot((LV) < pv_); \
    cnds(LV, pv_, ~(sm_ ^ tm_)); \
}
// one stage applied to all 8 seed lists (interleaved for ILP)
#define S8(AJ, K, J) { BSTG(sa0, AJ, K, J) BSTG(sa1, AJ, K, J) BSTG(sa2, AJ, K, J) BSTG(sa3, AJ, K, J) \
                       BSTG(sb0, AJ, K, J) BSTG(sb1, AJ, K, J) BSTG(sb2, AJ, K, J) BSTG(sb3, AJ, K, J) }
// bitonic-merge cleanup stage applied to the 4 merged lists (ascending: k=128)
#define C4(AJ, J) { BSTG(sa0, AJ, 128, J) BSTG(sa1, AJ, 128, J) BSTG(sa2, AJ, 128, J) BSTG(sa3, AJ, 128, J) }

// record within-radius hits of D (rare), in index order
#define REC(D, RV, RI, NV, BASE) { \
    unsigned long long mr_ = __ballot(r2f >= (D)); \
    while (mr_) { \
        int sl_ = (int)__builtin_ctzll(mr_); mr_ &= mr_ - 1; \
        float v_ = readlane_f(D, sl_); \
        if (lane == (NV)) { RV = v_; RI = (BASE) + sl_; } \
        ++(NV); \
    } \
}

// ballot-filtered insertion, two candidates per iteration:
// lv' = min3(lv, max(lv[-1], w1), max(lv[-2], w2)) with w1 <= w2
// T may be stale (monotone non-increasing): over-accepts only, still exact.
#define INS2(D, LV, T) { \
    unsigned long long m_ = __ballot((D) < (T)); \
    while (m_) { \
        const int sl1_ = (int)__builtin_ctzll(m_); m_ &= m_ - 1; \
        const int b1_ = __builtin_amdgcn_readlane(__float_as_int(D), sl1_); \
        if (m_) { \
            const int sl2_ = (int)__builtin_ctzll(m_); m_ &= m_ - 1; \
            const int b2_ = __builtin_amdgcn_readlane(__float_as_int(D), sl2_); \
            const int w1_ = (b1_ < b2_) ? b1_ : b2_; \
            const int w2_ = (b1_ < b2_) ? b2_ : b1_; \
            float p1_ = shr1_f(LV); \
            float p2_ = shr1_f(p1_); \
            float t1_ = maxs_f(p1_, w1_); \
            float t2_ = maxs_f(p2_, w2_); \
            LV = min3_f(LV, t1_, t2_); \
        } else { \
            LV = med3_vsv(shr1_f(LV), b1_, LV); \
        } \
    } \
}

__device__ __forceinline__ void epilogue(
    float* __restrict__ out, const float* __restrict__ sden, const float4* ssp,
    int b, int tb, int lane,
    float lv, float rv, int ri, int nv,
    float tx, float ty, float tz)
{
    const float invdd = 1.0f / (RADIUS_F + 1e-6f);
    int vflag = 0; int vidx = -1; float dsum = 0.f; int vcnt = 0;
    const int sdb = b * NS_;
    const int nvc = (nv > 64) ? 64 : nv;
    for (int s = 0; s < nvc; ++s) {
        float vr = readlane_f(rv, s);
        int   ir = __builtin_amdgcn_readlane(ri, s);
        int rank = (int)__popcll(__ballot(lv < vr));
        for (int q = 0; q < s; ++q)                  // ties: earlier index first
            rank += (readlane_f(rv, q) == vr) ? 1 : 0;
        if (rank < K_) {
            dsum += sden[sdb + ir];
            ++vcnt;
            if (lane == rank) { vflag = 1; vidx = ir; }
        }
    }
    float px = 0.f, py = 0.f, pz = 0.f;
    if (vflag) {
        float4 spv = ssp[vidx];
        px = spv.x * -0.5f;                          // exact un-prescale
        py = spv.y * -0.5f;
        pz = spv.z * -0.5f;
    }
    const float tsx = tx * invdd, tsy = ty * invdd, tsz = tz * invdd;
    if (lane < K_) {
        const int pb = tb * K_ + lane;
        float3 p3;
        p3.x = (vflag ? px * invdd : 0.0f) - tsx;
        p3.y = (vflag ? py * invdd : 0.0f) - tsy;
        p3.z = (vflag ? pz * invdd : 0.0f) - tsz;
        *reinterpret_cast<float3*>(&out[O_PATCH + pb * 3]) = p3;
        float2 ix;
        ix.x = (float)b;
        ix.y = (float)vidx;                          // -1 when invalid
        *reinterpret_cast<float2*>(&out[O_IDX + pb * 2]) = ix;
        out[O_DIST + tb * K_ + lane] = sqrtf(fmaxf(lv, 1e-9f)) * invdd;
    }
    if (lane == 0) {
        out[O_SIZE + tb] = (float)vcnt;
        out[O_WD + tb]   = dsum / (float)(K_ - vcnt);
    }
}

__global__ __launch_bounds__(TPB, 8) void group_points_kernel(
    const float* __restrict__ src,
    const float* __restrict__ tgt,
    const float* __restrict__ sden,
    float* __restrict__ out)
{
    __shared__ float4 s_sp[NS_];                     // 32 KiB

    const int tid  = threadIdx.x;
    const int lane = tid & 63;
    const int wav  = tid >> 6;
    const int b    = blockIdx.x / BLOCKS_PER_BATCH;
    const int tile = blockIdx.x % BLOCKS_PER_BATCH;

    for (int j = tid; j < NS_; j += TPB) {
        const float* p = src + (b * NS_ + j) * 3;
        float x = p[0], y = p[1], z = p[2];
        float r1 = __fadd_rn(__fadd_rn(__fmul_rn(x, x), __fmul_rn(y, y)), __fmul_rn(z, z));
        s_sp[j] = make_float4(-2.f * x, -2.f * y, -2.f * z, r1);
    }
    if (blockIdx.x == 0 && tid == 0) {
        out[O_RAD + 0] = RADIUS_F;
        out[O_RAD + 1] = RADIUS_F;
    }
    __syncthreads();

    const float r2f = __fmul_rn(RADIUS_F, RADIUS_F);
    // precomputed xor-partner / reverse bpermute addresses
    const int a1  = (lane ^ 1)  << 2;
    const int a2  = (lane ^ 2)  << 2;
    const int a4  = (lane ^ 4)  << 2;
    const int a8  = (lane ^ 8)  << 2;
    const int a16 = (lane ^ 16) << 2;
    const int a32 = (lane ^ 32) << 2;
    const int arev = (63 - lane) << 2;

    for (int gp = 0; gp < TGT_PER_WAVE / 4; ++gp) {
        const int t0 = tile * TGT_PER_BLOCK + wav * TGT_PER_WAVE + gp * 4;
        const int tb0 = b * NT_ + t0;
        const float* tp = tgt + tb0 * 3;
        const float tx0 = tp[0],  ty0 = tp[1],  tz0 = tp[2];
        const float tx1 = tp[3],  ty1 = tp[4],  tz1 = tp[5];
        const float tx2 = tp[6],  ty2 = tp[7],  tz2 = tp[8];
        const float tx3 = tp[9],  ty3 = tp[10], tz3 = tp[11];
        const float r00 = __fadd_rn(__fadd_rn(__fmul_rn(tx0, tx0), __fmul_rn(ty0, ty0)), __fmul_rn(tz0, tz0));
        const float r01 = __fadd_rn(__fadd_rn(__fmul_rn(tx1, tx1), __fmul_rn(ty1, ty1)), __fmul_rn(tz1, tz1));
        const float r02 = __fadd_rn(__fadd_rn(__fmul_rn(tx2, tx2), __fmul_rn(ty2, ty2)), __fmul_rn(tz2, tz2));
        const float r03 = __fadd_rn(__fadd_rn(__fmul_rn(tx3, tx3), __fmul_rn(ty3, ty3)), __fmul_rn(tz3, tz3));

        float rv0 = 0.f, rv1 = 0.f, rv2 = 0.f, rv3 = 0.f;
        int   ri0 = 0,   ri1 = 0,   ri2 = 0,   ri3 = 0;
        int   nv0 = 0,   nv1 = 0,   nv2 = 0,   nv3 = 0;

        // ---- seed: chunks 0+1 -> 128-element sorted seed, keep low 64 ----
        float4 sp0 = s_sp[lane];
        float4 sp1 = s_sp[64 + lane];
        float sa0 = dist_f(tx0, ty0, tz0, r00, sp0);
        float sa1 = dist_f(tx1, ty1, tz1, r01, sp0);
        float sa2 = dist_f(tx2, ty2, tz2, r02, sp0);
        float sa3 = dist_f(tx3, ty3, tz3, r03, sp0);
        float sb0 = dist_f(tx0, ty0, tz0, r00, sp1);
        float sb1 = dist_f(tx1, ty1, tz1, r01, sp1);
        float sb2 = dist_f(tx2, ty2, tz2, r02, sp1);
        float sb3 = dist_f(tx3, ty3, tz3, r03, sp1);
        // radius-record (rare): gate all 8 behind one combined ballot
        {
            float g8 = fminf(fminf(fminf(sa0, sa1), fminf(sa2, sa3)),
                             fminf(fminf(sb0, sb1), fminf(sb2, sb3)));
            if (__ballot(g8 <= r2f)) {
                REC(sa0, rv0, ri0, nv0, 0)  REC(sb0, rv0, ri0, nv0, 64)
                REC(sa1, rv1, ri1, nv1, 0)  REC(sb1, rv1, ri1, nv1, 64)
                REC(sa2, rv2, ri2, nv2, 0)  REC(sb2, rv2, ri2, nv2, 64)
                REC(sa3, rv3, ri3, nv3, 0)  REC(sb3, rv3, ri3, nv3, 64)
            }
        }
        // sort all 8 lists ascending (stage-interleaved)
        S8(a1, 2, 1)
        S8(a2, 4, 2)   S8(a1, 4, 1)
        S8(a4, 8, 4)   S8(a2, 8, 2)   S8(a1, 8, 1)
        S8(a8, 16, 8)  S8(a4, 16, 4)  S8(a2, 16, 2)  S8(a1, 16, 1)
        S8(a16, 32, 16) S8(a8, 32, 8) S8(a4, 32, 4)  S8(a2, 32, 2)  S8(a1, 32, 1)
        S8(a32, 64, 32) S8(a16, 64, 16) S8(a8, 64, 8) S8(a4, 64, 4) S8(a2, 64, 2) S8(a1, 64, 1)
        // merge: low half of (sa asc, sb desc) is bitonic; 6-stage cleanup
        sa0 = fminf(sa0, bperm_f(arev, sb0));
        sa1 = fminf(sa1, bperm_f(arev, sb1));
        sa2 = fminf(sa2, bperm_f(arev, sb2));
        sa3 = fminf(sa3, bperm_f(arev, sb3));
        C4(a32, 32) C4(a16, 16) C4(a8, 8) C4(a4, 4) C4(a2, 2) C4(a1, 1)
        float T0 = readlane_f(sa0, 31);
        float T1 = readlane_f(sa1, 31);
        float T2 = readlane_f(sa2, 31);
        float T3 = readlane_f(sa3, 31);

        // ---- scan chunks 2..31: 4 independent insert pipelines ----
        for (int c = 2; c < NCHUNK; ++c) {
            float4 sp = s_sp[(c << 6) + lane];
            float d0 = dist_f(tx0, ty0, tz0, r00, sp);
            float d1 = dist_f(tx1, ty1, tz1, r01, sp);
            float d2 = dist_f(tx2, ty2, tz2, r02, sp);
            float d3 = dist_f(tx3, ty3, tz3, r03, sp);

            // rare: any lane of any target within radius -> record in index order
            float g_ = fminf(fminf(d0, d1), fminf(d2, d3));
            if (__ballot(g_ <= r2f)) {
                const int base = c << 6;
                REC(d0, rv0, ri0, nv0, base)
                REC(d1, rv1, ri1, nv1, base)
                REC(d2, rv2, ri2, nv2, base)
                REC(d3, rv3, ri3, nv3, base)
            }

            INS2(d0, sa0, T0)
            INS2(d1, sa1, T1)
            INS2(d2, sa2, T2)
            INS2(d3, sa3, T3)
            if (c & 1) {                 // lazy threshold refresh (safe: stale T only over-accepts)
                T0 = readlane_f(sa0, 31);
                T1 = readlane_f(sa1, 31);
                T2 = readlane_f(sa2, 31);
                T3 = readlane_f(sa3, 31);
            }
        }

        epilogue(out, sden, s_sp, b, tb0,     lane, sa0, rv0, ri0, nv0, tx0, ty0, tz0);
        epilogue(out, sden, s_sp, b, tb0 + 1, lane, sa1, rv1, ri1, nv1, tx1, ty1, tz1);
        epilogue(out, sden, s_sp, b, tb0 + 2, lane, sa2, rv2, ri2, nv2, tx2, ty2, tz2);
        epilogue(out, sden, s_sp, b, tb0 + 3, lane, sa3, rv3, ri3, nv3, tx3, ty3, tz3);
    }
}

extern "C" void kernel_launch(void* const* d_in, const int* in_sizes, int n_in,
                              void* d_out, int out_size, void* d_ws, size_t ws_size,
                              hipStream_t stream) {
    const float* src  = (const float*)d_in[0];   // (B,Ns,3)
    const float* tgt  = (const float*)d_in[1];   // (B,Nt,3)
    const float* sden = (const float*)d_in[2];   // (B,Ns,1)
    // d_in[3] = target_density: feeds only a dead value in the reference
    float* out = (float*)d_out;

    dim3 grid(B_ * BLOCKS_PER_BATCH);            // 1024 blocks
    group_points_kernel<<<grid, TPB, 0, stream>>>(src, tgt, sden, out);
}

// Round 9
// 195.543 us; speedup vs baseline: 1.1438x; 1.1438x over previous
//
#include <hip/hip_runtime.h>
#include <math.h>

// Problem constants (from reference setup_inputs)
constexpr int B_  = 2;
constexpr int NS_ = 2048;
constexpr int NT_ = 32768;
constexpr int K_  = 32;
#define RADIUS_F 0.08f

constexpr int TPB = 512;                                 // 8 waves
constexpr int TGT_PER_WAVE = 4;                          // one quad per wave
constexpr int TGT_PER_BLOCK = 8 * TGT_PER_WAVE;          // 32
constexpr int BLOCKS_PER_BATCH = NT_ / TGT_PER_BLOCK;    // 1024
constexpr int NCHUNK = NS_ / 64;                         // 32

// Output layout: tuple concatenated flat, in return order (all float).
// Total elements ~12.7M -> all offsets fit int (saves 64-bit addr chains).
constexpr int SZ_PATCH = B_ * NT_ * K_ * 3;
constexpr int SZ_IDX   = B_ * NT_ * K_ * 2;
constexpr int SZ_SIZE  = B_ * NT_;
constexpr int SZ_RAD   = B_;
constexpr int SZ_DIST  = B_ * NT_ * K_;
constexpr int O_PATCH = 0;
constexpr int O_IDX   = O_PATCH + SZ_PATCH;
constexpr int O_SIZE  = O_IDX + SZ_IDX;
constexpr int O_RAD   = O_SIZE + SZ_SIZE;
constexpr int O_DIST  = O_RAD + SZ_RAD;
constexpr int O_WD    = O_DIST + SZ_DIST;

// Compile-time bitonic take-min direction mask for stage (k,j).
// Note tm_mask(128,j) == tm_mask(64,j) for lanes 0..63, so CLEAN reuses M_64_*.
constexpr unsigned long long tm_mask(int k, int j) {
    unsigned long long m = 0;
    for (int l = 0; l < 64; ++l)
        if (((l & k) == 0) == ((l & j) == 0)) m |= 1ull << l;
    return m;
}

__device__ __forceinline__ float readlane_f(float v, int l) {
    return __int_as_float(__builtin_amdgcn_readlane(__float_as_int(v), l));
}
__device__ __forceinline__ float bperm_f(int addr, float v) {
    return __int_as_float(__builtin_amdgcn_ds_bpermute(addr, __float_as_int(v)));
}
// lane i <- lane i-1 across the whole wave; lane 0 <- 0 (wave_shr:1, bound_ctrl)
__device__ __forceinline__ float shr1_f(float v) {
    return __int_as_float(__builtin_amdgcn_update_dpp(0, __float_as_int(v),
                                                      0x138, 0xF, 0xF, true));
}
// quad_perm DPP partner (xor1: 0xB1, xor2: 0x4E)
template<int CTRL>
__device__ __forceinline__ float dppq_f(float v) {
    return __int_as_float(__builtin_amdgcn_update_dpp(0, __float_as_int(v),
                                                      CTRL, 0xF, 0xF, true));
}
// sorted single insert: lv' = med3(lv[lane-1], v, lv); v broadcast bits in SGPR
__device__ __forceinline__ float med3_vsv(float pv, int vbits, float lv) {
    float r;
    asm("v_med3_f32 %0, %1, %2, %3" : "=v"(r) : "v"(pv), "s"(vbits), "v"(lv));
    return r;
}
// max(p, sgpr-broadcast w)
__device__ __forceinline__ float maxs_f(float p, int wbits) {
    float r;
    asm("v_max_f32 %0, %1, %2" : "=v"(r) : "s"(wbits), "v"(p));
    return r;
}
__device__ __forceinline__ float min3_f(float a, float b, float c) {
    float r;
    asm("v_min3_f32 %0, %1, %2, %3" : "=v"(r) : "v"(a), "v"(b), "v"(c));
    return r;
}
// r = mask ? a : b  (cndmask with SGPR-pair mask)
__device__ __forceinline__ float cndf(float a, float b, unsigned long long mask) {
    float r;
    asm("v_cndmask_b32 %0, %2, %1, %3" : "=v"(r) : "v"(a), "v"(b), "s"(mask));
    return r;
}
// sp = (-2x, -2y, -2z, r1): d = (r0 + dot') + r1, bitwise == XLA's (r0-2*dot)+r1
// (pre-scale by -2 is exact; x2 scaling commutes with fp rounding)
__device__ __forceinline__ float dist_f(float tx, float ty, float tz, float r0, float4 sp) {
    float dot2 = __fadd_rn(__fadd_rn(__fmul_rn(tx, sp.x), __fmul_rn(ty, sp.y)), __fmul_rn(tz, sp.z));
    return __fadd_rn(__fadd_rn(r0, dot2), sp.w);
}

// compare-exchange, bpermute partner: 3 VALU + 1 DS, 0 SALU.
// M bit set -> lane keeps min (identical to ballot form incl. ties).
#define CEXB(LV, AJ, M) { \
    float p_ = bperm_f(AJ, LV); \
    float mn_ = fminf(LV, p_); \
    float mx_ = fmaxf(LV, p_); \
    LV = cndf(mn_, mx_, M); \
}
// compare-exchange, DPP quad_perm partner: 4 VALU, 0 SALU, 0 DS.
#define CEXD(LV, CTRL, M) { \
    float p_ = dppq_f<CTRL>(LV); \
    float mn_ = fminf(LV, p_); \
    float mx_ = fmaxf(LV, p_); \
    LV = cndf(mn_, mx_, M); \
}
// one stage applied to all 8 seed lists (interleaved for ILP)
#define S8B(AJ, M) { CEXB(sa0, AJ, M) CEXB(sa1, AJ, M) CEXB(sa2, AJ, M) CEXB(sa3, AJ, M) \
                     CEXB(sb0, AJ, M) CEXB(sb1, AJ, M) CEXB(sb2, AJ, M) CEXB(sb3, AJ, M) }
#define S8D(CTRL, M) { CEXD(sa0, CTRL, M) CEXD(sa1, CTRL, M) CEXD(sa2, CTRL, M) CEXD(sa3, CTRL, M) \
                       CEXD(sb0, CTRL, M) CEXD(sb1, CTRL, M) CEXD(sb2, CTRL, M) CEXD(sb3, CTRL, M) }
// cleanup stage applied to the 4 merged lists
#define C4B(AJ, M) { CEXB(sa0, AJ, M) CEXB(sa1, AJ, M) CEXB(sa2, AJ, M) CEXB(sa3, AJ, M) }
#define C4D(CTRL, M) { CEXD(sa0, CTRL, M) CEXD(sa1, CTRL, M) CEXD(sa2, CTRL, M) CEXD(sa3, CTRL, M) }

// record within-radius hits of D (rare), in index order
#define REC(D, RV, RI, NV, BASE) { \
    unsigned long long mr_ = __ballot(r2f >= (D)); \
    while (mr_) { \
        int sl_ = (int)__builtin_ctzll(mr_); mr_ &= mr_ - 1; \
        float v_ = readlane_f(D, sl_); \
        if (lane == (NV)) { RV = v_; RI = (BASE) + sl_; } \
        ++(NV); \
    } \
}

// ballot-filtered insertion, two candidates per iteration:
// lv' = min3(lv, max(lv[-1], w1), max(lv[-2], w2)) with w1 <= w2
#define INS2(D, LV, T) { \
    unsigned long long m_ = __ballot((D) < (T)); \
    while (m_) { \
        const int sl1_ = (int)__builtin_ctzll(m_); m_ &= m_ - 1; \
        const int b1_ = __builtin_amdgcn_readlane(__float_as_int(D), sl1_); \
        if (m_) { \
            const int sl2_ = (int)__builtin_ctzll(m_); m_ &= m_ - 1; \
            const int b2_ = __builtin_amdgcn_readlane(__float_as_int(D), sl2_); \
            const int w1_ = (b1_ < b2_) ? b1_ : b2_; \
            const int w2_ = (b1_ < b2_) ? b2_ : b1_; \
            float p1_ = shr1_f(LV); \
            float p2_ = shr1_f(p1_); \
            float t1_ = maxs_f(p1_, w1_); \
            float t2_ = maxs_f(p2_, w2_); \
            LV = min3_f(LV, t1_, t2_); \
        } else { \
            LV = med3_vsv(shr1_f(LV), b1_, LV); \
        } \
    } \
}

__device__ __forceinline__ void epilogue(
    float* __restrict__ out, const float* __restrict__ sden, const float4* ssp,
    int b, int tb, int lane,
    float lv, float rv, int ri, int nv,
    float tx, float ty, float tz)
{
    const float invdd = 1.0f / (RADIUS_F + 1e-6f);
    int vflag = 0; int vidx = -1; float dsum = 0.f; int vcnt = 0;
    const int sdb = b * NS_;
    const int nvc = (nv > 64) ? 64 : nv;
    for (int s = 0; s < nvc; ++s) {
        float vr = readlane_f(rv, s);
        int   ir = __builtin_amdgcn_readlane(ri, s);
        int rank = (int)__popcll(__ballot(lv < vr));
        for (int q = 0; q < s; ++q)                  // ties: earlier index first
            rank += (readlane_f(rv, q) == vr) ? 1 : 0;
        if (rank < K_) {
            dsum += sden[sdb + ir];
            ++vcnt;
            if (lane == rank) { vflag = 1; vidx = ir; }
        }
    }
    float px = 0.f, py = 0.f, pz = 0.f;
    if (vflag) {
        float4 spv = ssp[vidx];
        px = spv.x * -0.5f;                          // exact un-prescale
        py = spv.y * -0.5f;
        pz = spv.z * -0.5f;
    }
    const float tsx = tx * invdd, tsy = ty * invdd, tsz = tz * invdd;
    if (lane < K_) {
        const int pb = tb * K_ + lane;
        float3 p3;
        p3.x = (vflag ? px * invdd : 0.0f) - tsx;
        p3.y = (vflag ? py * invdd : 0.0f) - tsy;
        p3.z = (vflag ? pz * invdd : 0.0f) - tsz;
        *reinterpret_cast<float3*>(&out[O_PATCH + pb * 3]) = p3;
        float2 ix;
        ix.x = (float)b;
        ix.y = (float)vidx;                          // -1 when invalid
        *reinterpret_cast<float2*>(&out[O_IDX + pb * 2]) = ix;
        out[O_DIST + tb * K_ + lane] = sqrtf(fmaxf(lv, 1e-9f)) * invdd;
    }
    if (lane == 0) {
        out[O_SIZE + tb] = (float)vcnt;
        out[O_WD + tb]   = dsum / (float)(K_ - vcnt);
    }
}

__global__ __launch_bounds__(TPB, 8) void group_points_kernel(
    const float* __restrict__ src,
    const float* __restrict__ tgt,
    const float* __restrict__ sden,
    float* __restrict__ out)
{
    __shared__ float4 s_sp[NS_];                     // 32 KiB

    const int tid  = threadIdx.x;
    const int lane = tid & 63;
    const int wav  = tid >> 6;
    const int b    = blockIdx.x / BLOCKS_PER_BATCH;
    const int tile = blockIdx.x % BLOCKS_PER_BATCH;

    for (int j = tid; j < NS_; j += TPB) {
        const float* p = src + (b * NS_ + j) * 3;
        float x = p[0], y = p[1], z = p[2];
        float r1 = __fadd_rn(__fadd_rn(__fmul_rn(x, x), __fmul_rn(y, y)), __fmul_rn(z, z));
        s_sp[j] = make_float4(-2.f * x, -2.f * y, -2.f * z, r1);
    }
    if (blockIdx.x == 0 && tid == 0) {
        out[O_RAD + 0] = RADIUS_F;
        out[O_RAD + 1] = RADIUS_F;
    }
    __syncthreads();

    const float r2f = __fmul_rn(RADIUS_F, RADIUS_F);
    // bpermute partner / reverse addresses
    const int a4   = (lane ^ 4)  << 2;
    const int a8   = (lane ^ 8)  << 2;
    const int a16  = (lane ^ 16) << 2;
    const int a32  = (lane ^ 32) << 2;
    const int arev = (63 - lane) << 2;
    // hoisted take-min direction masks (SGPR pairs)
    const unsigned long long M_2_1   = tm_mask(2, 1);
    const unsigned long long M_4_2   = tm_mask(4, 2),  M_4_1  = tm_mask(4, 1);
    const unsigned long long M_8_4   = tm_mask(8, 4),  M_8_2  = tm_mask(8, 2),  M_8_1  = tm_mask(8, 1);
    const unsigned long long M_16_8  = tm_mask(16, 8), M_16_4 = tm_mask(16, 4), M_16_2 = tm_mask(16, 2), M_16_1 = tm_mask(16, 1);
    const unsigned long long M_32_16 = tm_mask(32, 16), M_32_8 = tm_mask(32, 8), M_32_4 = tm_mask(32, 4), M_32_2 = tm_mask(32, 2), M_32_1 = tm_mask(32, 1);
    const unsigned long long M_64_32 = tm_mask(64, 32), M_64_16 = tm_mask(64, 16), M_64_8 = tm_mask(64, 8), M_64_4 = tm_mask(64, 4), M_64_2 = tm_mask(64, 2), M_64_1 = tm_mask(64, 1);

    const int t0 = tile * TGT_PER_BLOCK + wav * TGT_PER_WAVE;
    const int tb0 = b * NT_ + t0;
    const float* tp = tgt + tb0 * 3;
    const float tx0 = tp[0],  ty0 = tp[1],  tz0 = tp[2];
    const float tx1 = tp[3],  ty1 = tp[4],  tz1 = tp[5];
    const float tx2 = tp[6],  ty2 = tp[7],  tz2 = tp[8];
    const float tx3 = tp[9],  ty3 = tp[10], tz3 = tp[11];
    const float r00 = __fadd_rn(__fadd_rn(__fmul_rn(tx0, tx0), __fmul_rn(ty0, ty0)), __fmul_rn(tz0, tz0));
    const float r01 = __fadd_rn(__fadd_rn(__fmul_rn(tx1, tx1), __fmul_rn(ty1, ty1)), __fmul_rn(tz1, tz1));
    const float r02 = __fadd_rn(__fadd_rn(__fmul_rn(tx2, tx2), __fmul_rn(ty2, ty2)), __fmul_rn(tz2, tz2));
    const float r03 = __fadd_rn(__fadd_rn(__fmul_rn(tx3, tx3), __fmul_rn(ty3, ty3)), __fmul_rn(tz3, tz3));

    float rv0 = 0.f, rv1 = 0.f, rv2 = 0.f, rv3 = 0.f;
    int   ri0 = 0,   ri1 = 0,   ri2 = 0,   ri3 = 0;
    int   nv0 = 0,   nv1 = 0,   nv2 = 0,   nv3 = 0;

    // ---- seed: chunks 0+1 -> 128-element sorted seed, keep low 64 ----
    float4 sp0 = s_sp[lane];
    float4 sp1 = s_sp[64 + lane];
    float sa0 = dist_f(tx0, ty0, tz0, r00, sp0);
    float sa1 = dist_f(tx1, ty1, tz1, r01, sp0);
    float sa2 = dist_f(tx2, ty2, tz2, r02, sp0);
    float sa3 = dist_f(tx3, ty3, tz3, r03, sp0);
    float sb0 = dist_f(tx0, ty0, tz0, r00, sp1);
    float sb1 = dist_f(tx1, ty1, tz1, r01, sp1);
    float sb2 = dist_f(tx2, ty2, tz2, r02, sp1);
    float sb3 = dist_f(tx3, ty3, tz3, r03, sp1);
    // radius-record (rare): gate all 8 behind one combined ballot
    {
        float g8 = fminf(fminf(fminf(sa0, sa1), fminf(sa2, sa3)),
                         fminf(fminf(sb0, sb1), fminf(sb2, sb3)));
        if (__ballot(g8 <= r2f)) {
            REC(sa0, rv0, ri0, nv0, 0)  REC(sb0, rv0, ri0, nv0, 64)
            REC(sa1, rv1, ri1, nv1, 0)  REC(sb1, rv1, ri1, nv1, 64)
            REC(sa2, rv2, ri2, nv2, 0)  REC(sb2, rv2, ri2, nv2, 64)
            REC(sa3, rv3, ri3, nv3, 0)  REC(sb3, rv3, ri3, nv3, 64)
        }
    }
    // sort all 8 lists ascending (stage-interleaved; DPP for j=1,2)
    S8D(0xB1, M_2_1)
    S8D(0x4E, M_4_2)   S8D(0xB1, M_4_1)
    S8B(a4, M_8_4)     S8D(0x4E, M_8_2)   S8D(0xB1, M_8_1)
    S8B(a8, M_16_8)    S8B(a4, M_16_4)    S8D(0x4E, M_16_2)  S8D(0xB1, M_16_1)
    S8B(a16, M_32_16)  S8B(a8, M_32_8)    S8B(a4, M_32_4)    S8D(0x4E, M_32_2)  S8D(0xB1, M_32_1)
    S8B(a32, M_64_32)  S8B(a16, M_64_16)  S8B(a8, M_64_8)    S8B(a4, M_64_4)    S8D(0x4E, M_64_2)  S8D(0xB1, M_64_1)
    // merge: low half of (sa asc, sb desc) is bitonic; 6-stage cleanup
    sa0 = fminf(sa0, bperm_f(arev, sb0));
    sa1 = fminf(sa1, bperm_f(arev, sb1));
    sa2 = fminf(sa2, bperm_f(arev, sb2));
    sa3 = fminf(sa3, bperm_f(arev, sb3));
    C4B(a32, M_64_32) C4B(a16, M_64_16) C4B(a8, M_64_8) C4B(a4, M_64_4) C4D(0x4E, M_64_2) C4D(0xB1, M_64_1)
    float T0 = readlane_f(sa0, 31);
    float T1 = readlane_f(sa1, 31);
    float T2 = readlane_f(sa2, 31);
    float T3 = readlane_f(sa3, 31);

    // ---- scan chunks 2..31: 4 independent insert pipelines, exact T refresh ----
    for (int c = 2; c < NCHUNK; ++c) {
        float4 sp = s_sp[(c << 6) + lane];
        float d0 = dist_f(tx0, ty0, tz0, r00, sp);
        float d1 = dist_f(tx1, ty1, tz1, r01, sp);
        float d2 = dist_f(tx2, ty2, tz2, r02, sp);
        float d3 = dist_f(tx3, ty3, tz3, r03, sp);

        // rare: any lane of any target within radius -> record in index order
        float g_ = fminf(fminf(d0, d1), fminf(d2, d3));
        if (__ballot(g_ <= r2f)) {
            const int base = c << 6;
            REC(d0, rv0, ri0, nv0, base)
            REC(d1, rv1, ri1, nv1, base)
            REC(d2, rv2, ri2, nv2, base)
            REC(d3, rv3, ri3, nv3, base)
        }

        INS2(d0, sa0, T0)  T0 = readlane_f(sa0, 31);
        INS2(d1, sa1, T1)  T1 = readlane_f(sa1, 31);
        INS2(d2, sa2, T2)  T2 = readlane_f(sa2, 31);
        INS2(d3, sa3, T3)  T3 = readlane_f(sa3, 31);
    }

    epilogue(out, sden, s_sp, b, tb0,     lane, sa0, rv0, ri0, nv0, tx0, ty0, tz0);
    epilogue(out, sden, s_sp, b, tb0 + 1, lane, sa1, rv1, ri1, nv1, tx1, ty1, tz1);
    epilogue(out, sden, s_sp, b, tb0 + 2, lane, sa2, rv2, ri2, nv2, tx2, ty2, tz2);
    epilogue(out, sden, s_sp, b, tb0 + 3, lane, sa3, rv3, ri3, nv3, tx3, ty3, tz3);
}

extern "C" void kernel_launch(void* const* d_in, const int* in_sizes, int n_in,
                              void* d_out, int out_size, void* d_ws, size_t ws_size,
                              hipStream_t stream) {
    const float* src  = (const float*)d_in[0];   // (B,Ns,3)
    const float* tgt  = (const float*)d_in[1];   // (B,Nt,3)
    const float* sden = (const float*)d_in[2];   // (B,Ns,1)
    // d_in[3] = target_density: feeds only a dead value in the reference
    float* out = (float*)d_out;

    dim3 grid(B_ * BLOCKS_PER_BATCH);            // 2048 blocks
    group_points_kernel<<<grid, TPB, 0, stream>>>(src, tgt, sden, out);
}